// Round 1
// baseline (1235.395 us; speedup 1.0000x reference)
//
#include <hip/hip_runtime.h>
#include <math.h>

// ---------------------------------------------------------------------------
// Mamba forward, fp32 baseline.
// Pipeline:
//   K1 gemm_nt<1>: xz = hidden @ in_proj_w^T  -> x_raw (b,ch,l), zbuf (b,l,ch)
//   K2 conv_silu_tr: causal conv4 + bias + SiLU, transpose -> xt (b,l,ch)
//   K3 gemm_nt<0>: x_dbl = xt @ x_proj_w^T (N=96)
//   K4 gemm_nt<2>: delta = softplus(x_dbl[:,:64] @ dt_proj_w^T + dt_b) (b,l,d)
//   K5-7 chunked selective scan (32 chunks x 64 steps), y overwrites delta
//   K8 gemm_nt<0>: out = y @ out_proj_w^T
// Workspace: ~154 MB laid out below.
// ---------------------------------------------------------------------------

#define DMODEL 1024
#define DINNER 2048
#define DSTATE 16
#define DTRANK 64
#define BSZ    2
#define LSEQ   2048
#define NCHUNK 32
#define CLEN   64
#define NQROW  (BSZ*DINNER*4)   // 16384 quad-rows (b,d,quad-of-4-states)

__device__ __forceinline__ float silu_f(float v) {
    return v / (1.f + __expf(-v));
}
__device__ __forceinline__ float softplus_f(float v) {
    return (v > 20.f) ? v : log1pf(expf(v));
}

// ---------------------------------------------------------------------------
// Generic NT GEMM: C[m,n] = sum_k A[m*lda+k] * B[n*ldb+k]
// 64x64 tile, BK=16, 256 threads, 4x4 microtile.
// M assumed multiple of 64 (always 4096 here). N guarded.
// EPI 0: plain store C[m*ldc+n]
// EPI 1: xz split: n<2048 -> C = x_raw (b,ch,l); n>=2048 -> C2 = z (b,l,ch)
// EPI 2: softplus(acc + bias[n]) -> C[m*ldc+n]
// ---------------------------------------------------------------------------
template<int EPI>
__global__ __launch_bounds__(256) void gemm_nt(
    const float* __restrict__ A, int lda,
    const float* __restrict__ B, int ldb,
    float* __restrict__ C, int ldc,
    float* __restrict__ C2,
    const float* __restrict__ bias,
    int N, int K)
{
    __shared__ float As[16][68];   // +4 pad keeps rows 16B aligned, breaks conflicts
    __shared__ float Bs[16][68];
    const int m0 = blockIdx.y * 64;
    const int n0 = blockIdx.x * 64;
    const int t  = threadIdx.x;
    const int tx = t & 15, ty = t >> 4;     // microtile coords
    const int lrow = t >> 2, kq = (t & 3) * 4;  // staging coords

    const float* Aptr = A + (size_t)(m0 + lrow) * lda + kq;
    const float* Bptr = B + (size_t)(n0 + lrow) * ldb + kq;
    const bool bok = (n0 + lrow) < N;

    float acc[4][4];
#pragma unroll
    for (int i = 0; i < 4; i++)
#pragma unroll
        for (int j = 0; j < 4; j++) acc[i][j] = 0.f;

    for (int k0 = 0; k0 < K; k0 += 16) {
        float4 av = *(const float4*)(Aptr + k0);
        float4 bv = make_float4(0.f, 0.f, 0.f, 0.f);
        if (bok) bv = *(const float4*)(Bptr + k0);
        __syncthreads();   // previous iter's reads done before overwrite
        As[kq + 0][lrow] = av.x; As[kq + 1][lrow] = av.y;
        As[kq + 2][lrow] = av.z; As[kq + 3][lrow] = av.w;
        Bs[kq + 0][lrow] = bv.x; Bs[kq + 1][lrow] = bv.y;
        Bs[kq + 2][lrow] = bv.z; Bs[kq + 3][lrow] = bv.w;
        __syncthreads();
#pragma unroll
        for (int kk = 0; kk < 16; ++kk) {
            float4 a4 = *(const float4*)&As[kk][ty * 4];
            float4 b4 = *(const float4*)&Bs[kk][tx * 4];
            float ar[4] = {a4.x, a4.y, a4.z, a4.w};
            float br[4] = {b4.x, b4.y, b4.z, b4.w};
#pragma unroll
            for (int i = 0; i < 4; i++)
#pragma unroll
                for (int j = 0; j < 4; j++)
                    acc[i][j] = fmaf(ar[i], br[j], acc[i][j]);
        }
    }

    if (EPI == 1) {
        // m = b*LSEQ + l ; tiles never straddle b (2048 % 64 == 0)
        int b = m0 >> 11;
        int l = (m0 & (LSEQ - 1)) + ty * 4;
        if (n0 < DINNER) {
            // x part: x_raw[b][e][l], contiguous in l (= m)
#pragma unroll
            for (int j = 0; j < 4; j++) {
                int e = n0 + tx * 4 + j;
                float4 v = make_float4(acc[0][j], acc[1][j], acc[2][j], acc[3][j]);
                *(float4*)(C + ((size_t)b * DINNER + e) * LSEQ + l) = v;
            }
        } else {
            // z part: z[b][l][e'], contiguous in e' (= n)
#pragma unroll
            for (int i = 0; i < 4; i++) {
                float4 v = make_float4(acc[i][0], acc[i][1], acc[i][2], acc[i][3]);
                *(float4*)(C2 + ((size_t)b * LSEQ + l + i) * DINNER + (n0 - DINNER) + tx * 4) = v;
            }
        }
    } else {
        int n = n0 + tx * 4;
        if (n < N) {
#pragma unroll
            for (int i = 0; i < 4; i++) {
                int m = m0 + ty * 4 + i;
                float4 v = make_float4(acc[i][0], acc[i][1], acc[i][2], acc[i][3]);
                if (EPI == 2) {
                    v.x = softplus_f(v.x + bias[n + 0]);
                    v.y = softplus_f(v.y + bias[n + 1]);
                    v.z = softplus_f(v.z + bias[n + 2]);
                    v.w = softplus_f(v.w + bias[n + 3]);
                }
                *(float4*)(C + (size_t)m * ldc + n) = v;
            }
        }
    }
}

// ---------------------------------------------------------------------------
// Causal conv width-4 + bias + SiLU, with (b,ch,l) -> (b,l,ch) transpose
// via a 32x32 LDS tile. grid (L/32, CH/32, B), 256 threads.
// ---------------------------------------------------------------------------
__global__ __launch_bounds__(256) void conv_silu_tr(
    const float* __restrict__ xraw, const float* __restrict__ convw,
    const float* __restrict__ convb, float* __restrict__ xt)
{
    __shared__ float tile[32][33];
    const int b  = blockIdx.z;
    const int l0 = blockIdx.x * 32;
    const int c0 = blockIdx.y * 32;
    const int tl = threadIdx.x & 31;
    const int tc = threadIdx.x >> 5;   // 0..7
    const int l  = l0 + tl;
#pragma unroll
    for (int s = 0; s < 4; ++s) {
        int ch = c0 + tc + s * 8;
        const float* row = xraw + ((size_t)b * DINNER + ch) * LSEQ;
        float w0 = convw[ch * 4 + 0], w1 = convw[ch * 4 + 1];
        float w2 = convw[ch * 4 + 2], w3 = convw[ch * 4 + 3];
        float x0 = (l >= 3) ? row[l - 3] : 0.f;
        float x1 = (l >= 2) ? row[l - 2] : 0.f;
        float x2 = (l >= 1) ? row[l - 1] : 0.f;
        float x3 = row[l];
        float acc = convb[ch] + w0 * x0 + w1 * x1 + w2 * x2 + w3 * x3;
        tile[tc + s * 8][tl] = silu_f(acc);
    }
    __syncthreads();
    const int cx = threadIdx.x & 31;
    const int ly = threadIdx.x >> 5;
#pragma unroll
    for (int s = 0; s < 4; ++s) {
        int ll = ly + s * 8;
        xt[((size_t)b * LSEQ + l0 + ll) * DINNER + c0 + cx] = tile[cx][ll];
    }
}

// ---------------------------------------------------------------------------
// Chunked selective scan. State h[b,d,n], recurrence over l:
//   dA = exp(delta*A) ; h = dA*h + (delta*x)*B_l ; y = sum_n h*C_l
// Phase A: per chunk, P = prod dA, S = local final state (h0 = 0)
// Phase B: per (b,d,n), sequential prefix over 32 chunks -> H (chunk inits)
// Phase C: replay chunk with correct init, produce y (+D*x, *silu(z)),
//          overwriting the delta buffer in place.
// Thread = one (b,d, quad-of-4 states, chunk). Quad reduce via shfl_xor.
// ---------------------------------------------------------------------------
__global__ __launch_bounds__(256) void scan_phaseA(
    const float* __restrict__ xdbl, const float* __restrict__ delta,
    const float* __restrict__ xt, const float* __restrict__ A_log,
    float* __restrict__ Pbuf, float* __restrict__ Sbuf)
{
    int id = blockIdx.x * 256 + threadIdx.x;   // NQROW*NCHUNK
    int qr = id & (NQROW - 1);
    int c  = id >> 14;
    int q  = qr & 3;
    int rowbd = qr >> 2;
    int d = rowbd & (DINNER - 1);
    int b = rowbd >> 11;
    float A[4], P[4], S[4];
#pragma unroll
    for (int j = 0; j < 4; j++) {
        A[j] = -expf(A_log[d * DSTATE + 4 * q + j]);
        P[j] = 1.f; S[j] = 0.f;
    }
    const size_t base0 = ((size_t)b * LSEQ) * DINNER + d;
    for (int l = c * CLEN; l < c * CLEN + CLEN; ++l) {
        size_t off = base0 + (size_t)l * DINNER;
        float dv = delta[off];
        float xv = xt[off];
        const float* xr = xdbl + ((size_t)b * LSEQ + l) * 96;
        float4 Bv = *(const float4*)(xr + DTRANK + 4 * q);
        float dx = dv * xv;
        float Bj[4] = {Bv.x, Bv.y, Bv.z, Bv.w};
#pragma unroll
        for (int j = 0; j < 4; j++) {
            float dA = __expf(dv * A[j]);
            P[j] *= dA;
            S[j] = dA * S[j] + dx * Bj[j];
        }
    }
    size_t o = (size_t)c * (NQROW * 4) + (size_t)qr * 4;
    *(float4*)(Pbuf + o) = make_float4(P[0], P[1], P[2], P[3]);
    *(float4*)(Sbuf + o) = make_float4(S[0], S[1], S[2], S[3]);
}

__global__ __launch_bounds__(256) void scan_phaseB(
    const float* __restrict__ Pbuf, const float* __restrict__ Sbuf,
    float* __restrict__ Hbuf)
{
    int r = blockIdx.x * 256 + threadIdx.x;   // 65536 state rows
    float run = 0.f;
    for (int c = 0; c < NCHUNK; ++c) {
        size_t o = (size_t)c * (NQROW * 4) + r;
        Hbuf[o] = run;
        run = Pbuf[o] * run + Sbuf[o];
    }
}

__global__ __launch_bounds__(256) void scan_phaseC(
    const float* __restrict__ xdbl, const float* __restrict__ xt,
    const float* __restrict__ zbuf, const float* __restrict__ A_log,
    const float* __restrict__ Dvec, const float* __restrict__ Hbuf,
    float* __restrict__ y /* in-place over delta */)
{
    int id = blockIdx.x * 256 + threadIdx.x;
    int qr = id & (NQROW - 1);
    int c  = id >> 14;
    int q  = qr & 3;
    int rowbd = qr >> 2;
    int d = rowbd & (DINNER - 1);
    int b = rowbd >> 11;
    float A[4], h[4];
#pragma unroll
    for (int j = 0; j < 4; j++) A[j] = -expf(A_log[d * DSTATE + 4 * q + j]);
    float4 h4 = *(const float4*)(Hbuf + (size_t)c * (NQROW * 4) + (size_t)qr * 4);
    h[0] = h4.x; h[1] = h4.y; h[2] = h4.z; h[3] = h4.w;
    float Dd = Dvec[d];
    const size_t base0 = ((size_t)b * LSEQ) * DINNER + d;
    for (int l = c * CLEN; l < c * CLEN + CLEN; ++l) {
        size_t off = base0 + (size_t)l * DINNER;
        float dv = y[off];        // delta (read before in-place overwrite)
        float xv = xt[off];
        const float* xr = xdbl + ((size_t)b * LSEQ + l) * 96;
        float4 Bv = *(const float4*)(xr + DTRANK + 4 * q);
        float4 Cv = *(const float4*)(xr + DTRANK + DSTATE + 4 * q);
        float dx = dv * xv;
        float Bj[4] = {Bv.x, Bv.y, Bv.z, Bv.w};
        float Cj[4] = {Cv.x, Cv.y, Cv.z, Cv.w};
        float yp = 0.f;
#pragma unroll
        for (int j = 0; j < 4; j++) {
            float dA = __expf(dv * A[j]);
            h[j] = dA * h[j] + dx * Bj[j];
            yp = fmaf(h[j], Cj[j], yp);
        }
        yp += __shfl_xor(yp, 1);
        yp += __shfl_xor(yp, 2);
        if (q == 0) {
            float yv = yp + Dd * xv;
            float zv = zbuf[off];
            yv *= zv / (1.f + __expf(-zv));
            y[off] = yv;
        }
    }
}

// ---------------------------------------------------------------------------
extern "C" void kernel_launch(void* const* d_in, const int* in_sizes, int n_in,
                              void* d_out, int out_size, void* d_ws, size_t ws_size,
                              hipStream_t stream)
{
    const float* hidden     = (const float*)d_in[0];  // (2,2048,1024)
    const float* in_proj_w  = (const float*)d_in[1];  // (4096,1024)
    const float* conv_w     = (const float*)d_in[2];  // (2048,4)
    const float* conv_b     = (const float*)d_in[3];  // (2048,)
    const float* x_proj_w   = (const float*)d_in[4];  // (96,2048)
    const float* dt_proj_w  = (const float*)d_in[5];  // (2048,64)
    const float* dt_proj_b  = (const float*)d_in[6];  // (2048,)
    const float* A_log      = (const float*)d_in[7];  // (2048,16)
    const float* Dvec       = (const float*)d_in[8];  // (2048,)
    const float* out_proj_w = (const float*)d_in[9];  // (1024,2048)
    float* out = (float*)d_out;                        // (2,2048,1024)

    // workspace layout (floats)
    const size_t SZ_BLD = (size_t)BSZ * LSEQ * DINNER;   // 8388608
    float* x_raw = (float*)d_ws;                 // (b,ch,l)
    float* zbuf  = x_raw + SZ_BLD;               // (b,l,ch)
    float* xt    = zbuf + SZ_BLD;                // (b,l,ch)
    float* xdbl  = xt + SZ_BLD;                  // (b,l,96)
    float* dlt   = xdbl + (size_t)BSZ * LSEQ * 96;   // (b,l,d) delta, then y
    float* Pbuf  = dlt + SZ_BLD;                 // (chunk, 65536)
    float* Sbuf  = Pbuf + (size_t)NCHUNK * NQROW * 4;
    float* Hbuf  = Sbuf + (size_t)NCHUNK * NQROW * 4;

    const int M = BSZ * LSEQ;   // 4096

    // K1: xz = hidden @ in_proj_w^T, split into x_raw / zbuf
    gemm_nt<1><<<dim3(2 * DINNER / 64, M / 64), 256, 0, stream>>>(
        hidden, DMODEL, in_proj_w, DMODEL, x_raw, 0, zbuf, nullptr,
        2 * DINNER, DMODEL);

    // K2: conv + SiLU + transpose -> xt
    conv_silu_tr<<<dim3(LSEQ / 32, DINNER / 32, BSZ), 256, 0, stream>>>(
        x_raw, conv_w, conv_b, xt);

    // K3: x_dbl = xt @ x_proj_w^T  (N=96)
    gemm_nt<0><<<dim3(2, M / 64), 256, 0, stream>>>(
        xt, DINNER, x_proj_w, DINNER, xdbl, 96, nullptr, nullptr,
        96, DINNER);

    // K4: delta = softplus(x_dbl[:, :64] @ dt_proj_w^T + dt_proj_b)
    gemm_nt<2><<<dim3(DINNER / 64, M / 64), 256, 0, stream>>>(
        xdbl, 96, dt_proj_w, DTRANK, dlt, DINNER, nullptr, dt_proj_b,
        DINNER, DTRANK);

    // K5-7: chunked scan; y overwrites dlt
    scan_phaseA<<<(NQROW * NCHUNK) / 256, 256, 0, stream>>>(
        xdbl, dlt, xt, A_log, Pbuf, Sbuf);
    scan_phaseB<<<(NQROW * 4) / 256, 256, 0, stream>>>(Pbuf, Sbuf, Hbuf);
    scan_phaseC<<<(NQROW * NCHUNK) / 256, 256, 0, stream>>>(
        xdbl, xt, zbuf, A_log, Dvec, Hbuf, dlt);

    // K8: out = y @ out_proj_w^T
    gemm_nt<0><<<dim3(DMODEL / 64, M / 64), 256, 0, stream>>>(
        dlt, DINNER, out_proj_w, DINNER, out, DMODEL, nullptr, nullptr,
        DMODEL, DINNER);
}

// Round 2
// 500.037 us; speedup vs baseline: 2.4706x; 2.4706x over previous
//
#include <hip/hip_runtime.h>
#include <math.h>

// ---------------------------------------------------------------------------
// Mamba forward. Big GEMMs (in_proj, out_proj) in bf16 MFMA (m97 structure),
// small GEMMs + conv + scan in fp32.
//   cast: hidden->hbf, in_proj_w->wbf (bf16)
//   K1 gemm_bf16<1>: xz = hbf @ wbf^T -> xcpre (b,l,ch) fp32, zbuf (b,l,ch)
//   K2 conv_silu: causal conv4 + bias + SiLU -> xt (b,l,ch)
//   cast: out_proj_w -> owbf
//   K3 gemm_nt<0>: x_dbl = xt @ x_proj_w^T (N=96)
//   K4 gemm_nt<2>: delta = softplus(x_dbl[:,:64] @ dt_proj_w^T + dt_b)
//   K5-7 chunked scan (32 chunks x 64 steps); phaseC writes y as bf16 (ybf)
//   K8 gemm_bf16<0>: out = ybf @ owbf^T -> fp32 out
// ---------------------------------------------------------------------------

#define DMODEL 1024
#define DINNER 2048
#define DSTATE 16
#define DTRANK 64
#define BSZ    2
#define LSEQ   2048
#define NCHUNK 32
#define CLEN   64
#define NQROW  (BSZ*DINNER*4)   // 16384 quad-rows

typedef __attribute__((ext_vector_type(8))) short bf16x8;
typedef __attribute__((ext_vector_type(8))) unsigned short u16x8;
typedef __attribute__((ext_vector_type(4))) float f32x4;

__device__ __forceinline__ float silu_f(float v) {
    return v / (1.f + __expf(-v));
}
__device__ __forceinline__ float softplus_f(float v) {
    return (v > 20.f) ? v : log1pf(expf(v));
}
__device__ __forceinline__ unsigned short f2bf(float f) {
    unsigned int u = __float_as_uint(f);
    unsigned int r = (u + 0x7fffu + ((u >> 16) & 1u)) >> 16;   // RNE
    return (unsigned short)r;
}
__device__ __forceinline__ void gl_lds16(const void* g, void* l) {
    __builtin_amdgcn_global_load_lds(
        (const __attribute__((address_space(1))) unsigned int*)g,
        (__attribute__((address_space(3))) unsigned int*)l, 16, 0, 0);
}

// ---------------------------------------------------------------------------
// fp32 -> bf16 cast, 8 elems/thread
// ---------------------------------------------------------------------------
__global__ __launch_bounds__(256) void cast_bf16(
    const float* __restrict__ src, unsigned short* __restrict__ dst)
{
    size_t i = (size_t)blockIdx.x * 256 + threadIdx.x;
    float4 a = ((const float4*)src)[2 * i];
    float4 b = ((const float4*)src)[2 * i + 1];
    u16x8 v;
    v[0] = f2bf(a.x); v[1] = f2bf(a.y); v[2] = f2bf(a.z); v[3] = f2bf(a.w);
    v[4] = f2bf(b.x); v[5] = f2bf(b.y); v[6] = f2bf(b.z); v[7] = f2bf(b.w);
    *(u16x8*)(dst + 8 * i) = v;
}

// ---------------------------------------------------------------------------
// bf16 MFMA GEMM (NT): C[m,n] = sum_k A[m,k]*B[n,k]
// A: M x K bf16, B: N x K bf16, C fp32. 128x128 tile, BK=32, 256 thr (4 waves)
// EPI 0: C[m*ldc+n]
// EPI 1: n < DINNER -> C[m*DINNER+n] ; else -> C2[m*DINNER + n-DINNER]
// ---------------------------------------------------------------------------
template<int EPI>
__global__ __launch_bounds__(256) void gemm_bf16(
    const short* __restrict__ A, const short* __restrict__ B,
    float* __restrict__ C, int ldc, float* __restrict__ C2, int K)
{
    __shared__ __align__(16) short As[128 * 32];
    __shared__ __align__(16) short Bs[128 * 32];
    const int t = threadIdx.x;
    const int wave = t >> 6, lane = t & 63;
    const int m0 = blockIdx.y * 128, n0 = blockIdx.x * 128;
    const int wm = (wave & 1) * 64, wn = (wave >> 1) * 64;
    const int srow = t >> 2;            // 0..63 staging row (per 64-row half)
    const int sq = (t & 3) * 16;        // byte offset within 64B row

    const short* Ag = A + (size_t)(m0 + srow) * K;
    const short* Bg = B + (size_t)(n0 + srow) * K;
    char* AsL0 = (char*)As + wave * 1024;          // wave-uniform LDS bases
    char* AsL1 = (char*)As + 4096 + wave * 1024;
    char* BsL0 = (char*)Bs + wave * 1024;
    char* BsL1 = (char*)Bs + 4096 + wave * 1024;

    const int quad = lane >> 4, l16 = lane & 15;
    const int aoff = (wm + l16) * 32 + quad * 8;   // shorts
    const int boff = (wn + l16) * 32 + quad * 8;

    f32x4 acc[4][4];
#pragma unroll
    for (int i = 0; i < 4; i++)
#pragma unroll
        for (int j = 0; j < 4; j++) {
            f32x4 z = {0.f, 0.f, 0.f, 0.f};
            acc[i][j] = z;
        }

    for (int k0 = 0; k0 < K; k0 += 32) {
        __syncthreads();   // previous iter's LDS reads done
        gl_lds16((const char*)(Ag + k0) + sq, AsL0);
        gl_lds16((const char*)(Ag + (size_t)64 * K + k0) + sq, AsL1);
        gl_lds16((const char*)(Bg + k0) + sq, BsL0);
        gl_lds16((const char*)(Bg + (size_t)64 * K + k0) + sq, BsL1);
        __syncthreads();   // staging drained
        bf16x8 af[4], bfr[4];
#pragma unroll
        for (int i = 0; i < 4; i++) {
            af[i]  = *(const bf16x8*)(As + aoff + i * 16 * 32);
            bfr[i] = *(const bf16x8*)(Bs + boff + i * 16 * 32);
        }
#pragma unroll
        for (int i = 0; i < 4; i++)
#pragma unroll
            for (int j = 0; j < 4; j++)
                acc[i][j] = __builtin_amdgcn_mfma_f32_16x16x32_bf16(
                    af[i], bfr[j], acc[i][j], 0, 0, 0);
    }

    // C/D layout: col(n) = lane&15, row(m) = quad*4 + reg   [m89-verified]
#pragma unroll
    for (int i = 0; i < 4; i++) {
        int mrow = m0 + wm + i * 16 + quad * 4;
#pragma unroll
        for (int j = 0; j < 4; j++) {
            int n = n0 + wn + j * 16 + l16;
            float* dst;
            int ld;
            if (EPI == 1) { dst = (n0 < DINNER) ? C : (C2 - DINNER); ld = DINNER; }
            else          { dst = C; ld = ldc; }
#pragma unroll
            for (int r = 0; r < 4; r++)
                dst[(size_t)(mrow + r) * ld + n] = acc[i][j][r];
        }
    }
}

// ---------------------------------------------------------------------------
// fp32 NT GEMM (small GEMMs only). 64x64 tile, BK=16, 4x4 microtile.
// EPI 0: plain ; EPI 2: softplus(acc + bias[n])
// ---------------------------------------------------------------------------
template<int EPI>
__global__ __launch_bounds__(256) void gemm_nt(
    const float* __restrict__ A, int lda,
    const float* __restrict__ B, int ldb,
    float* __restrict__ C, int ldc,
    const float* __restrict__ bias,
    int N, int K)
{
    __shared__ float As[16][68];
    __shared__ float Bs[16][68];
    const int m0 = blockIdx.y * 64;
    const int n0 = blockIdx.x * 64;
    const int t  = threadIdx.x;
    const int tx = t & 15, ty = t >> 4;
    const int lrow = t >> 2, kq = (t & 3) * 4;

    const float* Aptr = A + (size_t)(m0 + lrow) * lda + kq;
    const float* Bptr = B + (size_t)(n0 + lrow) * ldb + kq;
    const bool bok = (n0 + lrow) < N;

    float acc[4][4];
#pragma unroll
    for (int i = 0; i < 4; i++)
#pragma unroll
        for (int j = 0; j < 4; j++) acc[i][j] = 0.f;

    for (int k0 = 0; k0 < K; k0 += 16) {
        float4 av = *(const float4*)(Aptr + k0);
        float4 bv = make_float4(0.f, 0.f, 0.f, 0.f);
        if (bok) bv = *(const float4*)(Bptr + k0);
        __syncthreads();
        As[kq + 0][lrow] = av.x; As[kq + 1][lrow] = av.y;
        As[kq + 2][lrow] = av.z; As[kq + 3][lrow] = av.w;
        Bs[kq + 0][lrow] = bv.x; Bs[kq + 1][lrow] = bv.y;
        Bs[kq + 2][lrow] = bv.z; Bs[kq + 3][lrow] = bv.w;
        __syncthreads();
#pragma unroll
        for (int kk = 0; kk < 16; ++kk) {
            float4 a4 = *(const float4*)&As[kk][ty * 4];
            float4 b4 = *(const float4*)&Bs[kk][tx * 4];
            float ar[4] = {a4.x, a4.y, a4.z, a4.w};
            float br[4] = {b4.x, b4.y, b4.z, b4.w};
#pragma unroll
            for (int i = 0; i < 4; i++)
#pragma unroll
                for (int j = 0; j < 4; j++)
                    acc[i][j] = fmaf(ar[i], br[j], acc[i][j]);
        }
    }

    int n = n0 + tx * 4;
    if (n < N) {
#pragma unroll
        for (int i = 0; i < 4; i++) {
            int m = m0 + ty * 4 + i;
            float4 v = make_float4(acc[i][0], acc[i][1], acc[i][2], acc[i][3]);
            if (EPI == 2) {
                v.x = softplus_f(v.x + bias[n + 0]);
                v.y = softplus_f(v.y + bias[n + 1]);
                v.z = softplus_f(v.z + bias[n + 2]);
                v.w = softplus_f(v.w + bias[n + 3]);
            }
            *(float4*)(C + (size_t)m * ldc + n) = v;
        }
    }
}

// ---------------------------------------------------------------------------
// Causal conv4 + bias + SiLU, (b,l,ch) layout in and out. 4 ch per thread.
// ---------------------------------------------------------------------------
__global__ __launch_bounds__(256) void conv_silu(
    const float* __restrict__ xc, const float* __restrict__ convw,
    const float* __restrict__ convb, float* __restrict__ xt)
{
    int i = blockIdx.x * 256 + threadIdx.x;   // (m, ch/4): 4096*512
    int c4 = i & 511;
    int m  = i >> 9;
    int l  = m & (LSEQ - 1);
    int ch = c4 * 4;
    const float4* base = (const float4*)xc + (size_t)m * 512 + c4;
    float4 zf = make_float4(0.f, 0.f, 0.f, 0.f);
    float4 x3 = base[0];
    float4 x2 = (l >= 1) ? base[-512]  : zf;
    float4 x1 = (l >= 2) ? base[-1024] : zf;
    float4 x0 = (l >= 3) ? base[-1536] : zf;
    float4 t0 = ((const float4*)convw)[ch + 0];
    float4 t1 = ((const float4*)convw)[ch + 1];
    float4 t2 = ((const float4*)convw)[ch + 2];
    float4 t3 = ((const float4*)convw)[ch + 3];
    float4 bv = ((const float4*)convb)[c4];
    float4 o;
    o.x = silu_f(bv.x + t0.x * x0.x + t0.y * x1.x + t0.z * x2.x + t0.w * x3.x);
    o.y = silu_f(bv.y + t1.x * x0.y + t1.y * x1.y + t1.z * x2.y + t1.w * x3.y);
    o.z = silu_f(bv.z + t2.x * x0.z + t2.y * x1.z + t2.z * x2.z + t2.w * x3.z);
    o.w = silu_f(bv.w + t3.x * x0.w + t3.y * x1.w + t3.z * x2.w + t3.w * x3.w);
    ((float4*)xt)[(size_t)m * 512 + c4] = o;
}

// ---------------------------------------------------------------------------
// Chunked selective scan (unchanged math from round 0)
// ---------------------------------------------------------------------------
__global__ __launch_bounds__(256) void scan_phaseA(
    const float* __restrict__ xdbl, const float* __restrict__ delta,
    const float* __restrict__ xt, const float* __restrict__ A_log,
    float* __restrict__ Pbuf, float* __restrict__ Sbuf)
{
    int id = blockIdx.x * 256 + threadIdx.x;
    int qr = id & (NQROW - 1);
    int c  = id >> 14;
    int q  = qr & 3;
    int rowbd = qr >> 2;
    int d = rowbd & (DINNER - 1);
    int b = rowbd >> 11;
    float A[4], P[4], S[4];
#pragma unroll
    for (int j = 0; j < 4; j++) {
        A[j] = -expf(A_log[d * DSTATE + 4 * q + j]);
        P[j] = 1.f; S[j] = 0.f;
    }
    const size_t base0 = ((size_t)b * LSEQ) * DINNER + d;
    for (int l = c * CLEN; l < c * CLEN + CLEN; ++l) {
        size_t off = base0 + (size_t)l * DINNER;
        float dv = delta[off];
        float xv = xt[off];
        const float* xr = xdbl + ((size_t)b * LSEQ + l) * 96;
        float4 Bv = *(const float4*)(xr + DTRANK + 4 * q);
        float dx = dv * xv;
        float Bj[4] = {Bv.x, Bv.y, Bv.z, Bv.w};
#pragma unroll
        for (int j = 0; j < 4; j++) {
            float dA = __expf(dv * A[j]);
            P[j] *= dA;
            S[j] = dA * S[j] + dx * Bj[j];
        }
    }
    size_t o = (size_t)c * (NQROW * 4) + (size_t)qr * 4;
    *(float4*)(Pbuf + o) = make_float4(P[0], P[1], P[2], P[3]);
    *(float4*)(Sbuf + o) = make_float4(S[0], S[1], S[2], S[3]);
}

__global__ __launch_bounds__(256) void scan_phaseB(
    const float* __restrict__ Pbuf, const float* __restrict__ Sbuf,
    float* __restrict__ Hbuf)
{
    int r = blockIdx.x * 256 + threadIdx.x;
    float run = 0.f;
    for (int c = 0; c < NCHUNK; ++c) {
        size_t o = (size_t)c * (NQROW * 4) + r;
        Hbuf[o] = run;
        run = Pbuf[o] * run + Sbuf[o];
    }
}

__global__ __launch_bounds__(256) void scan_phaseC(
    const float* __restrict__ xdbl, const float* __restrict__ dlt,
    const float* __restrict__ xt, const float* __restrict__ zbuf,
    const float* __restrict__ A_log, const float* __restrict__ Dvec,
    const float* __restrict__ Hbuf, unsigned short* __restrict__ ybf)
{
    int id = blockIdx.x * 256 + threadIdx.x;
    int qr = id & (NQROW - 1);
    int c  = id >> 14;
    int q  = qr & 3;
    int rowbd = qr >> 2;
    int d = rowbd & (DINNER - 1);
    int b = rowbd >> 11;
    float A[4], h[4];
#pragma unroll
    for (int j = 0; j < 4; j++) A[j] = -expf(A_log[d * DSTATE + 4 * q + j]);
    float4 h4 = *(const float4*)(Hbuf + (size_t)c * (NQROW * 4) + (size_t)qr * 4);
    h[0] = h4.x; h[1] = h4.y; h[2] = h4.z; h[3] = h4.w;
    float Dd = Dvec[d];
    const size_t base0 = ((size_t)b * LSEQ) * DINNER + d;
    for (int l = c * CLEN; l < c * CLEN + CLEN; ++l) {
        size_t off = base0 + (size_t)l * DINNER;
        float dv = dlt[off];
        float xv = xt[off];
        const float* xr = xdbl + ((size_t)b * LSEQ + l) * 96;
        float4 Bv = *(const float4*)(xr + DTRANK + 4 * q);
        float4 Cv = *(const float4*)(xr + DTRANK + DSTATE + 4 * q);
        float dx = dv * xv;
        float Bj[4] = {Bv.x, Bv.y, Bv.z, Bv.w};
        float Cj[4] = {Cv.x, Cv.y, Cv.z, Cv.w};
        float yp = 0.f;
#pragma unroll
        for (int j = 0; j < 4; j++) {
            float dA = __expf(dv * A[j]);
            h[j] = dA * h[j] + dx * Bj[j];
            yp = fmaf(h[j], Cj[j], yp);
        }
        yp += __shfl_xor(yp, 1);
        yp += __shfl_xor(yp, 2);
        if (q == 0) {
            float yv = yp + Dd * xv;
            float zv = zbuf[off];
            yv *= zv / (1.f + __expf(-zv));
            ybf[off] = f2bf(yv);
        }
    }
}

// ---------------------------------------------------------------------------
extern "C" void kernel_launch(void* const* d_in, const int* in_sizes, int n_in,
                              void* d_out, int out_size, void* d_ws, size_t ws_size,
                              hipStream_t stream)
{
    const float* hidden     = (const float*)d_in[0];
    const float* in_proj_w  = (const float*)d_in[1];
    const float* conv_w     = (const float*)d_in[2];
    const float* conv_b     = (const float*)d_in[3];
    const float* x_proj_w   = (const float*)d_in[4];
    const float* dt_proj_w  = (const float*)d_in[5];
    const float* dt_proj_b  = (const float*)d_in[6];
    const float* A_log      = (const float*)d_in[7];
    const float* Dvec       = (const float*)d_in[8];
    const float* out_proj_w = (const float*)d_in[9];
    float* out = (float*)d_out;

    // workspace (float units). Total 36.5M floats = 146 MB.
    const size_t MF = 1024 * 1024;
    float* ws = (float*)d_ws;
    float* xcpre = ws;                         // [0, 8M)  pre-conv x (b,l,ch)
    //   after conv, region reused:
    unsigned short* owbf = (unsigned short*)ws;          // [0,1M) out_proj bf16
    float* Pbuf  = ws + 1 * MF;                // [1M,3M)
    float* Sbuf  = ws + 3 * MF;                // [3M,5M)
    float* Hbuf  = ws + 5 * MF;                // [5M,7M)
    float* zbuf  = ws + 8 * MF;                // [8M,16M)
    float* xt    = ws + 16 * MF;               // [16M,24M)
    float* xdbl  = ws + 24 * MF;               // [24M, 24.5M)
    float* dlt   = ws + 24 * MF + MF / 2;      // [24.5M, 32.5M)
    unsigned short* hbf = (unsigned short*)(ws + 32 * MF + MF / 2); // 4M bf16
    unsigned short* wbf = (unsigned short*)(ws + 34 * MF + MF / 2); // 4M bf16
    unsigned short* ybf = hbf;                 // after K1, 8M bf16 (aliases)

    const int M = BSZ * LSEQ;   // 4096

    // casts for K1
    cast_bf16<<<2048, 256, 0, stream>>>(hidden, hbf);
    cast_bf16<<<2048, 256, 0, stream>>>(in_proj_w, wbf);

    // K1: xz = hidden @ in_proj_w^T (bf16 MFMA), split x/z
    gemm_bf16<1><<<dim3(2 * DINNER / 128, M / 128), 256, 0, stream>>>(
        (const short*)hbf, (const short*)wbf, xcpre, 0, zbuf, DMODEL);

    // K2: conv + SiLU
    conv_silu<<<(M * 512) / 256, 256, 0, stream>>>(xcpre, conv_w, conv_b, xt);

    // cast out_proj_w (xcpre region now dead)
    cast_bf16<<<1024, 256, 0, stream>>>(out_proj_w, owbf);

    // K3: x_dbl = xt @ x_proj_w^T (N=96)
    gemm_nt<0><<<dim3(2, M / 64), 256, 0, stream>>>(
        xt, DINNER, x_proj_w, DINNER, xdbl, 96, nullptr, 96, DINNER);

    // K4: delta = softplus(x_dbl[:,:64] @ dt_proj_w^T + dt_proj_b)
    gemm_nt<2><<<dim3(DINNER / 64, M / 64), 256, 0, stream>>>(
        xdbl, 96, dt_proj_w, DTRANK, dlt, DINNER, dt_proj_b, DINNER, DTRANK);

    // K5-7: chunked scan; phaseC emits bf16 y
    scan_phaseA<<<(NQROW * NCHUNK) / 256, 256, 0, stream>>>(
        xdbl, dlt, xt, A_log, Pbuf, Sbuf);
    scan_phaseB<<<(NQROW * 4) / 256, 256, 0, stream>>>(Pbuf, Sbuf, Hbuf);
    scan_phaseC<<<(NQROW * NCHUNK) / 256, 256, 0, stream>>>(
        xdbl, dlt, xt, zbuf, A_log, Dvec, Hbuf, ybf);

    // K8: out = y @ out_proj_w^T (bf16 MFMA)
    gemm_bf16<0><<<dim3(DMODEL / 128, M / 128), 256, 0, stream>>>(
        (const short*)ybf, (const short*)owbf, out, DMODEL, nullptr, DINNER);
}

// Round 3
// 397.085 us; speedup vs baseline: 3.1112x; 1.2593x over previous
//
#include <hip/hip_runtime.h>
#include <math.h>

// ---------------------------------------------------------------------------
// Mamba forward.
//   casts: hidden->hbf, in_proj_w->wbf, x_proj_w->xpwbf(128-row pad),
//          out_proj_w->owbf   (all bf16)
//   K1 gemm_bf16<1>: xz = hbf @ wbf^T -> xcpre (b,l,ch) fp32, zbuf fp32
//   K2 conv_silu: causal conv4 + bias + SiLU -> xtbf (b,l,ch) bf16
//   K3 gemm_xproj (split-K=16 MFMA) + reduce_xdbl -> xdbl fp32 (b,l,96)
//   K4 gemm_nt<2>: delta = softplus(x_dbl[:,:64] @ dt_proj_w^T + dt_b) fp32
//   K5-7 chunked scan (32 chunks x 64 steps); phaseC writes y bf16 (ybf)
//   K8 gemm_bf16<0>: out = ybf @ owbf^T -> fp32 out
// Round-3 change: K3 was 120us @ 5.6% occupancy (128 blocks). Now split-K
// MFMA with 512 blocks; xt carried as bf16 (conv writes 16MB not 48MB).
// ---------------------------------------------------------------------------

#define DMODEL 1024
#define DINNER 2048
#define DSTATE 16
#define DTRANK 64
#define BSZ    2
#define LSEQ   2048
#define NCHUNK 32
#define CLEN   64
#define NQROW  (BSZ*DINNER*4)   // 16384 quad-rows
#define SPLITK 16
#define KCH    (DINNER / SPLITK)   // 128
#define XDBL_N 96
#define XDBL_SZ (BSZ*LSEQ*XDBL_N)  // 393216

typedef __attribute__((ext_vector_type(8))) short bf16x8;
typedef __attribute__((ext_vector_type(8))) unsigned short u16x8;
typedef __attribute__((ext_vector_type(4))) unsigned short u16x4;
typedef __attribute__((ext_vector_type(4))) float f32x4;

__device__ __forceinline__ float silu_f(float v) {
    return v / (1.f + __expf(-v));
}
__device__ __forceinline__ float softplus_f(float v) {
    return (v > 20.f) ? v : log1pf(expf(v));
}
__device__ __forceinline__ unsigned short f2bf(float f) {
    unsigned int u = __float_as_uint(f);
    unsigned int r = (u + 0x7fffu + ((u >> 16) & 1u)) >> 16;   // RNE
    return (unsigned short)r;
}
__device__ __forceinline__ float bf2f(unsigned short u) {
    return __uint_as_float(((unsigned int)u) << 16);
}
__device__ __forceinline__ void gl_lds16(const void* g, void* l) {
    __builtin_amdgcn_global_load_lds(
        (const __attribute__((address_space(1))) unsigned int*)g,
        (__attribute__((address_space(3))) unsigned int*)l, 16, 0, 0);
}

// ---------------------------------------------------------------------------
__global__ __launch_bounds__(256) void cast_bf16(
    const float* __restrict__ src, unsigned short* __restrict__ dst)
{
    size_t i = (size_t)blockIdx.x * 256 + threadIdx.x;
    float4 a = ((const float4*)src)[2 * i];
    float4 b = ((const float4*)src)[2 * i + 1];
    u16x8 v;
    v[0] = f2bf(a.x); v[1] = f2bf(a.y); v[2] = f2bf(a.z); v[3] = f2bf(a.w);
    v[4] = f2bf(b.x); v[5] = f2bf(b.y); v[6] = f2bf(b.z); v[7] = f2bf(b.w);
    *(u16x8*)(dst + 8 * i) = v;
}

// x_proj_w (96 x 2048) -> bf16 padded to 128 rows (rows 96..127 zero)
__global__ __launch_bounds__(256) void cast_xpw(
    const float* __restrict__ src, unsigned short* __restrict__ dst)
{
    int i = blockIdx.x * 256 + threadIdx.x;   // 32768 threads, 8 elems each
    size_t o = (size_t)i * 8;
    int row = (int)(o >> 11);
    u16x8 v = {0, 0, 0, 0, 0, 0, 0, 0};
    if (row < 96) {
        float4 a = ((const float4*)src)[2 * i];
        float4 b = ((const float4*)src)[2 * i + 1];
        v[0] = f2bf(a.x); v[1] = f2bf(a.y); v[2] = f2bf(a.z); v[3] = f2bf(a.w);
        v[4] = f2bf(b.x); v[5] = f2bf(b.y); v[6] = f2bf(b.z); v[7] = f2bf(b.w);
    }
    *(u16x8*)(dst + o) = v;
}

// ---------------------------------------------------------------------------
// bf16 MFMA GEMM (NT): C[m,n] = sum_k A[m,k]*B[n,k]
// 128x128 tile, BK=32, 256 thr (4 waves), global_load_lds width-16 staging.
// EPI 0: C[m*ldc+n] ; EPI 1: n<DINNER -> C[m*DINNER+n] else C2[m*DINNER+n-D]
// ---------------------------------------------------------------------------
template<int EPI>
__global__ __launch_bounds__(256) void gemm_bf16(
    const short* __restrict__ A, const short* __restrict__ B,
    float* __restrict__ C, int ldc, float* __restrict__ C2, int K)
{
    __shared__ __align__(16) short As[128 * 32];
    __shared__ __align__(16) short Bs[128 * 32];
    const int t = threadIdx.x;
    const int wave = t >> 6, lane = t & 63;
    const int m0 = blockIdx.y * 128, n0 = blockIdx.x * 128;
    const int wm = (wave & 1) * 64, wn = (wave >> 1) * 64;
    const int srow = t >> 2;
    const int sq = (t & 3) * 16;

    const short* Ag = A + (size_t)(m0 + srow) * K;
    const short* Bg = B + (size_t)(n0 + srow) * K;
    char* AsL0 = (char*)As + wave * 1024;
    char* AsL1 = (char*)As + 4096 + wave * 1024;
    char* BsL0 = (char*)Bs + wave * 1024;
    char* BsL1 = (char*)Bs + 4096 + wave * 1024;

    const int quad = lane >> 4, l16 = lane & 15;
    const int aoff = (wm + l16) * 32 + quad * 8;
    const int boff = (wn + l16) * 32 + quad * 8;

    f32x4 acc[4][4];
#pragma unroll
    for (int i = 0; i < 4; i++)
#pragma unroll
        for (int j = 0; j < 4; j++) {
            f32x4 z = {0.f, 0.f, 0.f, 0.f};
            acc[i][j] = z;
        }

    for (int k0 = 0; k0 < K; k0 += 32) {
        __syncthreads();
        gl_lds16((const char*)(Ag + k0) + sq, AsL0);
        gl_lds16((const char*)(Ag + (size_t)64 * K + k0) + sq, AsL1);
        gl_lds16((const char*)(Bg + k0) + sq, BsL0);
        gl_lds16((const char*)(Bg + (size_t)64 * K + k0) + sq, BsL1);
        __syncthreads();
        bf16x8 af[4], bfr[4];
#pragma unroll
        for (int i = 0; i < 4; i++) {
            af[i]  = *(const bf16x8*)(As + aoff + i * 16 * 32);
            bfr[i] = *(const bf16x8*)(Bs + boff + i * 16 * 32);
        }
#pragma unroll
        for (int i = 0; i < 4; i++)
#pragma unroll
            for (int j = 0; j < 4; j++)
                acc[i][j] = __builtin_amdgcn_mfma_f32_16x16x32_bf16(
                    af[i], bfr[j], acc[i][j], 0, 0, 0);
    }

    // C/D layout: col(n) = lane&15, row(m) = quad*4 + reg
#pragma unroll
    for (int i = 0; i < 4; i++) {
        int mrow = m0 + wm + i * 16 + quad * 4;
#pragma unroll
        for (int j = 0; j < 4; j++) {
            int n = n0 + wn + j * 16 + l16;
            float* dst;
            int ld;
            if (EPI == 1) { dst = (n0 < DINNER) ? C : (C2 - DINNER); ld = DINNER; }
            else          { dst = C; ld = ldc; }
#pragma unroll
            for (int r = 0; r < 4; r++)
                dst[(size_t)(mrow + r) * ld + n] = acc[i][j][r];
        }
    }
}

// ---------------------------------------------------------------------------
// K3: x_dbl split-K MFMA. A = xtbf (4096 x 2048), B = xpwbf (128 x 2048,
// rows 96..127 zero). Each block: 128 M-rows x 96 N-cols x 128 K.
// grid (32, SPLITK). Partials -> ppart[kc][4096][96].
// ---------------------------------------------------------------------------
__global__ __launch_bounds__(256) void gemm_xproj(
    const short* __restrict__ Abf, const short* __restrict__ Bbf,
    float* __restrict__ ppart)
{
    __shared__ __align__(16) short As[128 * 32];
    __shared__ __align__(16) short Bs[128 * 32];
    const int t = threadIdx.x;
    const int wave = t >> 6, lane = t & 63;
    const int m0 = blockIdx.x * 128;
    const int kc = blockIdx.y;
    const int srow = t >> 2;
    const int sq = (t & 3) * 16;

    const short* Ag = Abf + (size_t)(m0 + srow) * DINNER;
    const short* Bg = Bbf + (size_t)srow * DINNER;
    char* AsL0 = (char*)As + wave * 1024;
    char* AsL1 = (char*)As + 4096 + wave * 1024;
    char* BsL0 = (char*)Bs + wave * 1024;
    char* BsL1 = (char*)Bs + 4096 + wave * 1024;

    const int quad = lane >> 4, l16 = lane & 15;
    const int wm = wave * 32;

    f32x4 acc[2][6];
#pragma unroll
    for (int i = 0; i < 2; i++)
#pragma unroll
        for (int j = 0; j < 6; j++) {
            f32x4 z = {0.f, 0.f, 0.f, 0.f};
            acc[i][j] = z;
        }

    for (int k0 = kc * KCH; k0 < kc * KCH + KCH; k0 += 32) {
        __syncthreads();
        gl_lds16((const char*)(Ag + k0) + sq, AsL0);
        gl_lds16((const char*)(Ag + (size_t)64 * DINNER + k0) + sq, AsL1);
        gl_lds16((const char*)(Bg + k0) + sq, BsL0);
        gl_lds16((const char*)(Bg + (size_t)64 * DINNER + k0) + sq, BsL1);
        __syncthreads();
        bf16x8 af[2], bfr[6];
#pragma unroll
        for (int i = 0; i < 2; i++)
            af[i] = *(const bf16x8*)(As + (wm + i * 16 + l16) * 32 + quad * 8);
#pragma unroll
        for (int j = 0; j < 6; j++)
            bfr[j] = *(const bf16x8*)(Bs + (j * 16 + l16) * 32 + quad * 8);
#pragma unroll
        for (int i = 0; i < 2; i++)
#pragma unroll
            for (int j = 0; j < 6; j++)
                acc[i][j] = __builtin_amdgcn_mfma_f32_16x16x32_bf16(
                    af[i], bfr[j], acc[i][j], 0, 0, 0);
    }

    float* dst = ppart + (size_t)kc * XDBL_SZ;
#pragma unroll
    for (int i = 0; i < 2; i++) {
        int mrow = m0 + wm + i * 16 + quad * 4;
#pragma unroll
        for (int j = 0; j < 6; j++) {
            int n = j * 16 + l16;
#pragma unroll
            for (int r = 0; r < 4; r++)
                dst[(size_t)(mrow + r) * XDBL_N + n] = acc[i][j][r];
        }
    }
}

__global__ __launch_bounds__(256) void reduce_xdbl(
    const float* __restrict__ ppart, float* __restrict__ xdbl)
{
    int i = blockIdx.x * 256 + threadIdx.x;   // XDBL_SZ threads
    float s = 0.f;
#pragma unroll
    for (int c = 0; c < SPLITK; c++) s += ppart[(size_t)c * XDBL_SZ + i];
    xdbl[i] = s;
}

// ---------------------------------------------------------------------------
// fp32 NT GEMM (K4 only). 64x64 tile, BK=16, 4x4 microtile.
// EPI 2: softplus(acc + bias[n])
// ---------------------------------------------------------------------------
template<int EPI>
__global__ __launch_bounds__(256) void gemm_nt(
    const float* __restrict__ A, int lda,
    const float* __restrict__ B, int ldb,
    float* __restrict__ C, int ldc,
    const float* __restrict__ bias,
    int N, int K)
{
    __shared__ float As[16][68];
    __shared__ float Bs[16][68];
    const int m0 = blockIdx.y * 64;
    const int n0 = blockIdx.x * 64;
    const int t  = threadIdx.x;
    const int tx = t & 15, ty = t >> 4;
    const int lrow = t >> 2, kq = (t & 3) * 4;

    const float* Aptr = A + (size_t)(m0 + lrow) * lda + kq;
    const float* Bptr = B + (size_t)(n0 + lrow) * ldb + kq;
    const bool bok = (n0 + lrow) < N;

    float acc[4][4];
#pragma unroll
    for (int i = 0; i < 4; i++)
#pragma unroll
        for (int j = 0; j < 4; j++) acc[i][j] = 0.f;

    for (int k0 = 0; k0 < K; k0 += 16) {
        float4 av = *(const float4*)(Aptr + k0);
        float4 bv = make_float4(0.f, 0.f, 0.f, 0.f);
        if (bok) bv = *(const float4*)(Bptr + k0);
        __syncthreads();
        As[kq + 0][lrow] = av.x; As[kq + 1][lrow] = av.y;
        As[kq + 2][lrow] = av.z; As[kq + 3][lrow] = av.w;
        Bs[kq + 0][lrow] = bv.x; Bs[kq + 1][lrow] = bv.y;
        Bs[kq + 2][lrow] = bv.z; Bs[kq + 3][lrow] = bv.w;
        __syncthreads();
#pragma unroll
        for (int kk = 0; kk < 16; ++kk) {
            float4 a4 = *(const float4*)&As[kk][ty * 4];
            float4 b4 = *(const float4*)&Bs[kk][tx * 4];
            float ar[4] = {a4.x, a4.y, a4.z, a4.w};
            float br[4] = {b4.x, b4.y, b4.z, b4.w};
#pragma unroll
            for (int i = 0; i < 4; i++)
#pragma unroll
                for (int j = 0; j < 4; j++)
                    acc[i][j] = fmaf(ar[i], br[j], acc[i][j]);
        }
    }

    int n = n0 + tx * 4;
    if (n < N) {
#pragma unroll
        for (int i = 0; i < 4; i++) {
            int m = m0 + ty * 4 + i;
            float4 v = make_float4(acc[i][0], acc[i][1], acc[i][2], acc[i][3]);
            if (EPI == 2) {
                v.x = softplus_f(v.x + bias[n + 0]);
                v.y = softplus_f(v.y + bias[n + 1]);
                v.z = softplus_f(v.z + bias[n + 2]);
                v.w = softplus_f(v.w + bias[n + 3]);
            }
            *(float4*)(C + (size_t)m * ldc + n) = v;
        }
    }
}

// ---------------------------------------------------------------------------
// Causal conv4 + bias + SiLU, (b,l,ch) fp32 in, bf16 out. 4 ch per thread.
// ---------------------------------------------------------------------------
__global__ __launch_bounds__(256) void conv_silu(
    const float* __restrict__ xc, const float* __restrict__ convw,
    const float* __restrict__ convb, unsigned short* __restrict__ xtbf)
{
    int i = blockIdx.x * 256 + threadIdx.x;   // (m, ch/4): 4096*512
    int c4 = i & 511;
    int m  = i >> 9;
    int l  = m & (LSEQ - 1);
    int ch = c4 * 4;
    const float4* base = (const float4*)xc + (size_t)m * 512 + c4;
    float4 zf = make_float4(0.f, 0.f, 0.f, 0.f);
    float4 x3 = base[0];
    float4 x2 = (l >= 1) ? base[-512]  : zf;
    float4 x1 = (l >= 2) ? base[-1024] : zf;
    float4 x0 = (l >= 3) ? base[-1536] : zf;
    float4 t0 = ((const float4*)convw)[ch + 0];
    float4 t1 = ((const float4*)convw)[ch + 1];
    float4 t2 = ((const float4*)convw)[ch + 2];
    float4 t3 = ((const float4*)convw)[ch + 3];
    float4 bv = ((const float4*)convb)[c4];
    u16x4 o;
    o[0] = f2bf(silu_f(bv.x + t0.x * x0.x + t0.y * x1.x + t0.z * x2.x + t0.w * x3.x));
    o[1] = f2bf(silu_f(bv.y + t1.x * x0.y + t1.y * x1.y + t1.z * x2.y + t1.w * x3.y));
    o[2] = f2bf(silu_f(bv.z + t2.x * x0.z + t2.y * x1.z + t2.z * x2.z + t2.w * x3.z));
    o[3] = f2bf(silu_f(bv.w + t3.x * x0.w + t3.y * x1.w + t3.z * x2.w + t3.w * x3.w));
    *(u16x4*)(xtbf + (size_t)m * DINNER + ch) = o;
}

// ---------------------------------------------------------------------------
// Chunked selective scan (x now bf16)
// ---------------------------------------------------------------------------
__global__ __launch_bounds__(256) void scan_phaseA(
    const float* __restrict__ xdbl, const float* __restrict__ delta,
    const unsigned short* __restrict__ xtbf, const float* __restrict__ A_log,
    float* __restrict__ Pbuf, float* __restrict__ Sbuf)
{
    int id = blockIdx.x * 256 + threadIdx.x;
    int qr = id & (NQROW - 1);
    int c  = id >> 14;
    int q  = qr & 3;
    int rowbd = qr >> 2;
    int d = rowbd & (DINNER - 1);
    int b = rowbd >> 11;
    float A[4], P[4], S[4];
#pragma unroll
    for (int j = 0; j < 4; j++) {
        A[j] = -expf(A_log[d * DSTATE + 4 * q + j]);
        P[j] = 1.f; S[j] = 0.f;
    }
    const size_t base0 = ((size_t)b * LSEQ) * DINNER + d;
    for (int l = c * CLEN; l < c * CLEN + CLEN; ++l) {
        size_t off = base0 + (size_t)l * DINNER;
        float dv = delta[off];
        float xv = bf2f(xtbf[off]);
        const float* xr = xdbl + ((size_t)b * LSEQ + l) * 96;
        float4 Bv = *(const float4*)(xr + DTRANK + 4 * q);
        float dx = dv * xv;
        float Bj[4] = {Bv.x, Bv.y, Bv.z, Bv.w};
#pragma unroll
        for (int j = 0; j < 4; j++) {
            float dA = __expf(dv * A[j]);
            P[j] *= dA;
            S[j] = dA * S[j] + dx * Bj[j];
        }
    }
    size_t o = (size_t)c * (NQROW * 4) + (size_t)qr * 4;
    *(float4*)(Pbuf + o) = make_float4(P[0], P[1], P[2], P[3]);
    *(float4*)(Sbuf + o) = make_float4(S[0], S[1], S[2], S[3]);
}

__global__ __launch_bounds__(256) void scan_phaseB(
    const float* __restrict__ Pbuf, const float* __restrict__ Sbuf,
    float* __restrict__ Hbuf)
{
    int r = blockIdx.x * 256 + threadIdx.x;
    float run = 0.f;
    for (int c = 0; c < NCHUNK; ++c) {
        size_t o = (size_t)c * (NQROW * 4) + r;
        Hbuf[o] = run;
        run = Pbuf[o] * run + Sbuf[o];
    }
}

__global__ __launch_bounds__(256) void scan_phaseC(
    const float* __restrict__ xdbl, const float* __restrict__ dlt,
    const unsigned short* __restrict__ xtbf, const float* __restrict__ zbuf,
    const float* __restrict__ A_log, const float* __restrict__ Dvec,
    const float* __restrict__ Hbuf, unsigned short* __restrict__ ybf)
{
    int id = blockIdx.x * 256 + threadIdx.x;
    int qr = id & (NQROW - 1);
    int c  = id >> 14;
    int q  = qr & 3;
    int rowbd = qr >> 2;
    int d = rowbd & (DINNER - 1);
    int b = rowbd >> 11;
    float A[4], h[4];
#pragma unroll
    for (int j = 0; j < 4; j++) A[j] = -expf(A_log[d * DSTATE + 4 * q + j]);
    float4 h4 = *(const float4*)(Hbuf + (size_t)c * (NQROW * 4) + (size_t)qr * 4);
    h[0] = h4.x; h[1] = h4.y; h[2] = h4.z; h[3] = h4.w;
    float Dd = Dvec[d];
    const size_t base0 = ((size_t)b * LSEQ) * DINNER + d;
    for (int l = c * CLEN; l < c * CLEN + CLEN; ++l) {
        size_t off = base0 + (size_t)l * DINNER;
        float dv = dlt[off];
        float xv = bf2f(xtbf[off]);
        const float* xr = xdbl + ((size_t)b * LSEQ + l) * 96;
        float4 Bv = *(const float4*)(xr + DTRANK + 4 * q);
        float4 Cv = *(const float4*)(xr + DTRANK + DSTATE + 4 * q);
        float dx = dv * xv;
        float Bj[4] = {Bv.x, Bv.y, Bv.z, Bv.w};
        float Cj[4] = {Cv.x, Cv.y, Cv.z, Cv.w};
        float yp = 0.f;
#pragma unroll
        for (int j = 0; j < 4; j++) {
            float dA = __expf(dv * A[j]);
            h[j] = dA * h[j] + dx * Bj[j];
            yp = fmaf(h[j], Cj[j], yp);
        }
        yp += __shfl_xor(yp, 1);
        yp += __shfl_xor(yp, 2);
        if (q == 0) {
            float yv = yp + Dd * xv;
            float zv = zbuf[off];
            yv *= zv / (1.f + __expf(-zv));
            ybf[off] = f2bf(yv);
        }
    }
}

// ---------------------------------------------------------------------------
extern "C" void kernel_launch(void* const* d_in, const int* in_sizes, int n_in,
                              void* d_out, int out_size, void* d_ws, size_t ws_size,
                              hipStream_t stream)
{
    const float* hidden     = (const float*)d_in[0];
    const float* in_proj_w  = (const float*)d_in[1];
    const float* conv_w     = (const float*)d_in[2];
    const float* conv_b     = (const float*)d_in[3];
    const float* x_proj_w   = (const float*)d_in[4];
    const float* dt_proj_w  = (const float*)d_in[5];
    const float* dt_proj_b  = (const float*)d_in[6];
    const float* A_log      = (const float*)d_in[7];
    const float* Dvec       = (const float*)d_in[8];
    const float* out_proj_w = (const float*)d_in[9];
    float* out = (float*)d_out;

    // workspace layout (float units). Total 31.5 MF = 126 MB.
    //  [0,8)    xcpre (K1->K2)  / dlt (K4->scanC)        [disjoint lifetimes]
    //  [8,16)   zbuf
    //  [16,20)  xtbf (bf16, 8M shorts)
    //  [20,26)  ppart (K3->reduce) / Pbuf,Sbuf,Hbuf (scan) [disjoint]
    //  [26,26.125) xpwbf (bf16)
    //  [26.125,26.5) xdbl
    //  [26.5,27.5) owbf (bf16)
    //  [27.5,31.5) hbf+wbf (casts->K1) / ybf (scanC->K8)  [disjoint]
    const size_t MF = 1024 * 1024;
    float* ws = (float*)d_ws;
    float* xcpre = ws;
    float* dlt   = ws;
    float* zbuf  = ws + 8 * MF;
    unsigned short* xtbf = (unsigned short*)(ws + 16 * MF);
    float* ppart = ws + 20 * MF;
    float* Pbuf  = ws + 20 * MF;
    float* Sbuf  = ws + 22 * MF;
    float* Hbuf  = ws + 24 * MF;
    unsigned short* xpwbf = (unsigned short*)(ws + 26 * MF);
    float* xdbl  = ws + 26 * MF + MF / 8;
    unsigned short* owbf = (unsigned short*)(ws + 26 * MF + MF / 2);
    unsigned short* hbf  = (unsigned short*)(ws + 27 * MF + MF / 2);
    unsigned short* wbf  = (unsigned short*)(ws + 29 * MF + MF / 2);
    unsigned short* ybf  = hbf;   // 4 MF region, reused after K1

    const int M = BSZ * LSEQ;   // 4096

    // casts
    cast_bf16<<<2048, 256, 0, stream>>>(hidden, hbf);
    cast_bf16<<<2048, 256, 0, stream>>>(in_proj_w, wbf);
    cast_xpw<<<128, 256, 0, stream>>>(x_proj_w, xpwbf);

    // K1: xz = hidden @ in_proj_w^T (bf16 MFMA), split x/z
    gemm_bf16<1><<<dim3(2 * DINNER / 128, M / 128), 256, 0, stream>>>(
        (const short*)hbf, (const short*)wbf, xcpre, 0, zbuf, DMODEL);

    // K2: conv + SiLU -> bf16 xt
    conv_silu<<<(M * 512) / 256, 256, 0, stream>>>(xcpre, conv_w, conv_b, xtbf);

    // cast out_proj_w (xcpre no longer needed as input after conv; owbf region
    // is independent anyway)
    cast_bf16<<<1024, 256, 0, stream>>>(out_proj_w, owbf);

    // K3: x_dbl split-K MFMA + reduce
    gemm_xproj<<<dim3(M / 128, SPLITK), 256, 0, stream>>>(
        (const short*)xtbf, (const short*)xpwbf, ppart);
    reduce_xdbl<<<XDBL_SZ / 256, 256, 0, stream>>>(ppart, xdbl);

    // K4: delta = softplus(x_dbl[:,:64] @ dt_proj_w^T + dt_proj_b)
    gemm_nt<2><<<dim3(DINNER / 64, M / 64), 256, 0, stream>>>(
        xdbl, 96, dt_proj_w, DTRANK, dlt, DINNER, dt_proj_b, DINNER, DTRANK);

    // K5-7: chunked scan; phaseC emits bf16 y
    scan_phaseA<<<(NQROW * NCHUNK) / 256, 256, 0, stream>>>(
        xdbl, dlt, xtbf, A_log, Pbuf, Sbuf);
    scan_phaseB<<<(NQROW * 4) / 256, 256, 0, stream>>>(Pbuf, Sbuf, Hbuf);
    scan_phaseC<<<(NQROW * NCHUNK) / 256, 256, 0, stream>>>(
        xdbl, dlt, xtbf, zbuf, A_log, Dvec, Hbuf, ybf);

    // K8: out = y @ out_proj_w^T (bf16 MFMA)
    gemm_bf16<0><<<dim3(DMODEL / 128, M / 128), 256, 0, stream>>>(
        (const short*)ybf, (const short*)owbf, out, DMODEL, nullptr, DINNER);
}